// Round 2
// baseline (1225.210 us; speedup 1.0000x reference)
//
#include <hip/hip_runtime.h>
#include <math.h>

// ---------------- problem constants ----------------
#define B_   8
#define CIN  128
#define H_   64
#define W_   128
#define D_   24
#define G_   8
#define HW_  (H_*W_)      // 8192
#define DHW_ (D_*HW_)     // 196608

// ---------------- workspace layout (float offsets) ----------------
// cv:  (B,8,D,H,W)  = 12,582,912 floats at 0
// x1:  (B,16,D,H,W) = 25,165,824 floats at 25,165,824
// x2:  (B,16,D,H,W) = 25,165,824 floats at 0 (aliases cv; cv dead by then)
// stats + prepacked weights tail at 50,331,648
#define CV_OFF    0
#define X1_OFF    25165824
#define X2_OFF    0
#define ST_OFF    50331648
#define GN1_STATS (ST_OFF + 0)     // 128 floats: (b,g)*2 {sum,sumsq}
#define GN1_SS    (ST_OFF + 128)   // 256 floats: (b,c)*2 {scale,shift}
#define GN2_STATS (ST_OFF + 384)
#define GN2_SS    (ST_OFF + 512)
#define GN3_STATS (ST_OFF + 768)
#define GN3_SS    (ST_OFF + 896)
#define ST_COUNT  1152
// prepacked weights: [kz][c][kyx][o] layouts for scalar (SGPR) streaming
#define WQ1_OFF   (ST_OFF + 2048)            // 3*8*9*16   = 3456
#define WQ2_OFF   (WQ1_OFF + 3456)           // 3*16*9*16  = 6912
#define WQF_OFF   (WQ2_OFF + 6912)           // 128*9*16   = 18432
#define WQ_TOTAL  (3456 + 6912 + 18432)      // 28800

// ---------------- output layout (float offsets in d_out) ----------------
#define OUT_D    0         // (B,1,H,W)  65536
#define OUT_SX   65536
#define OUT_SY   131072
#define OUT_FEAT 196608    // (B,16,H,W) 1048576
#define OUT_CONF 1245184

// ============================================================
// K0: prepack conv weights into [kz][c][kyx][o16] so the conv inner loops
// read them with wave-uniform addresses (-> scalar s_load path, off the
// LDS/VALU pipes).
// ============================================================
__global__ __launch_bounds__(256) void prepack_k(
    const float* __restrict__ w1, const float* __restrict__ w2,
    const float* __restrict__ fw, float* __restrict__ ws) {
  int i = blockIdx.x * 256 + threadIdx.x;
  if (i < 3456) {                       // wq1: CI=8
    int o = i & 15, r = i >> 4;
    int kyx = r % 9, r2 = r / 9;
    int c = r2 % 8, kz = r2 / 8;
    ws[WQ1_OFF + i] = w1[((o * 8 + c) * 3 + kz) * 9 + kyx];
  } else if (i < 3456 + 6912) {         // wq2: CI=16
    int j = i - 3456;
    int o = j & 15, r = j >> 4;
    int kyx = r % 9, r2 = r / 9;
    int c = r2 % 16, kz = r2 / 16;
    ws[WQ2_OFF + j] = w2[((o * 16 + c) * 3 + kz) * 9 + kyx];
  } else if (i < WQ_TOTAL) {            // wqf: [c128][kyx][o]
    int j = i - (3456 + 6912);
    int o = j & 15, r = j >> 4;
    int kyx = r % 9, c = r / 9;
    ws[WQF_OFF + j] = fw[(o * CIN + c) * 9 + kyx];
  }
}

// ============================================================
// K1: cost volume  cv[b,g,d,h,w] = mean_c16( fL[b,g*16+c,h,w]*fR[b,g*16+c,h,w-d] )
// block = one (b,h,d) row, 128 threads = w. d fastest in grid for L2 row reuse.
// ============================================================
__global__ __launch_bounds__(128) void cost_volume_k(
    const float* __restrict__ fL, const float* __restrict__ fR,
    float* __restrict__ cv) {
  int w  = threadIdx.x;
  int d  = blockIdx.x % D_;
  int bh = blockIdx.x / D_;
  int h  = bh & 63;
  int b  = bh >> 6;

  float acc[8];
#pragma unroll
  for (int g = 0; g < 8; ++g) acc[g] = 0.f;

  int wr = w - d;
  if (wr >= 0) {
    const float* pL = fL + (size_t)b * CIN * HW_ + h * W_ + w;
    const float* pR = fR + (size_t)b * CIN * HW_ + h * W_ + wr;
#pragma unroll
    for (int g = 0; g < 8; ++g) {
      float a = 0.f;
#pragma unroll
      for (int ci = 0; ci < 16; ++ci) {
        int c = g * 16 + ci;
        a = fmaf(pL[(size_t)c * HW_], pR[(size_t)c * HW_], a);
      }
      acc[g] = a;
    }
  }
  size_t base = ((size_t)(b * G_) * D_ + d) * HW_ + h * W_ + w;
#pragma unroll
  for (int g = 0; g < 8; ++g)
    cv[base + (size_t)g * D_ * HW_] = acc[g] * 0.0625f;
}

// ============================================================
// conv3d 3x3x3, CI->16, SAME. Tile 8x32 per block (256 thr), plane-at-a-time z.
// Weights stream from global with wave-uniform addresses (scalar path);
// activations stream from LDS. Optionally applies GroupNorm affine + SiLU
// to the INPUT during LDS fill (fusing the previous layer's gn+silu;
// zero-pad stays zero, matching the reference which pads post-activation).
// Writes raw conv output + accumulates GN stats (per b,group) via atomics.
// ============================================================
template <int CI, bool NORM>
__global__ __launch_bounds__(256) void conv3x3x3_k(
    const float* __restrict__ in, const float* __restrict__ wq,
    float* __restrict__ outp, float* __restrict__ stats,
    const float* __restrict__ nss) {
  int xt = blockIdx.x & 3;
  int yt = (blockIdx.x >> 2) & 7;
  int zb = blockIdx.x >> 5;
  int z  = zb % D_;
  int b  = zb / D_;

  __shared__ float plane[CI * 340];     // [c][10][34]
  __shared__ float ssl[32];             // per-channel scale,shift (if NORM)
  __shared__ float redS[4][8], redQ[4][8];

  int tid = threadIdx.x;
  if (NORM) {
    if (tid < 32) ssl[tid] = nss[b * 32 + tid];
  }

  float acc[16];
#pragma unroll
  for (int o = 0; o < 16; ++o) acc[o] = 0.f;

  int ty = tid >> 5, tx = tid & 31;
  int gy0 = yt * 8 - 1, gx0 = xt * 32 - 1;

  for (int kz = 0; kz < 3; ++kz) {
    int zi = z + kz - 1;
    __syncthreads();
    for (int i = tid; i < CI * 340; i += 256) {
      int xx = i % 34, r = i / 34;
      int yy = r % 10, c = r / 10;
      int gy = gy0 + yy, gx = gx0 + xx;
      float v = 0.f;
      if ((unsigned)zi < (unsigned)D_ && (unsigned)gy < (unsigned)H_ &&
          (unsigned)gx < (unsigned)W_) {
        v = in[(((size_t)(b * CI + c) * D_ + zi) * H_ + gy) * W_ + gx];
        if (NORM) {
          float t = fmaf(v, ssl[c * 2], ssl[c * 2 + 1]);
          v = t / (1.f + expf(-t));
        }
      }
      plane[i] = v;
    }
    __syncthreads();
    const float* wkz = wq + kz * CI * 144;   // uniform address stream
#pragma unroll
    for (int c = 0; c < CI; ++c) {
#pragma unroll
      for (int ky = 0; ky < 3; ++ky) {
#pragma unroll
        for (int kx = 0; kx < 3; ++kx) {
          float v = plane[(c * 10 + ty + ky) * 34 + tx + kx];
          const float* wp = wkz + (c * 9 + ky * 3 + kx) * 16;
#pragma unroll
          for (int o = 0; o < 16; ++o) acc[o] = fmaf(v, wp[o], acc[o]);
        }
      }
    }
  }

  int y = yt * 8 + ty, x = xt * 32 + tx;
  size_t obase = ((size_t)(b * 16) * D_ + z) * HW_ + y * W_ + x;
#pragma unroll
  for (int o = 0; o < 16; ++o)
    outp[obase + (size_t)o * DHW_] = acc[o];

  // GN stats: groups of 2 channels
  int lane = tid & 63, wid = tid >> 6;
#pragma unroll
  for (int g = 0; g < 8; ++g) {
    float s = acc[2 * g] + acc[2 * g + 1];
    float q = fmaf(acc[2 * g], acc[2 * g], acc[2 * g + 1] * acc[2 * g + 1]);
#pragma unroll
    for (int off = 32; off > 0; off >>= 1) {
      s += __shfl_down(s, off);
      q += __shfl_down(q, off);
    }
    if (lane == 0) { redS[wid][g] = s; redQ[wid][g] = q; }
  }
  __syncthreads();
  if (tid < 16) {
    int g = tid >> 1;
    float v = (tid & 1) ? (redQ[0][g] + redQ[1][g] + redQ[2][g] + redQ[3][g])
                        : (redS[0][g] + redS[1][g] + redS[2][g] + redS[3][g]);
    atomicAdd(&stats[b * 16 + tid], v);
  }
}

// ============================================================
// stats -> per (b,c) scale/shift:  xhat = x*scale + shift
// ============================================================
__global__ __launch_bounds__(128) void gn_scale_k(
    const float* __restrict__ stats, const float* __restrict__ gw,
    const float* __restrict__ gb, float* __restrict__ ss, float inv_count) {
  int i = threadIdx.x;  // b*16+c
  if (i < 128) {
    int c = i & 15, g = c >> 1, b = i >> 4;
    float sum = stats[(b * 8 + g) * 2];
    float sq  = stats[(b * 8 + g) * 2 + 1];
    float mean = sum * inv_count;
    float var  = sq * inv_count - mean * mean;
    float rstd = rsqrtf(var + 1e-5f);
    float sc = gw[c] * rstd;
    ss[i * 2] = sc;
    ss[i * 2 + 1] = gb[c] - mean * sc;
  }
}

// ============================================================
// conv3d 16->1 (+bias) fused with softmax over D, expectation + max-prob.
// Block = (b, 8x32 tile). Input x2 gets gn2-affine+SiLU on LDS fill.
// Weights read directly from w3 (uniform scalar path).
// Logits accumulate in LDS lg[26][256] (rows 0 and 25 are discard pads).
// ============================================================
__global__ __launch_bounds__(256) void conv3_softmax_k(
    const float* __restrict__ x2, const float* __restrict__ w3,
    const float* __restrict__ b3, const float* __restrict__ nss,
    float* __restrict__ out) {
  int xt = blockIdx.x & 3;
  int yt = (blockIdx.x >> 2) & 7;
  int b  = blockIdx.x >> 5;

  __shared__ float lg[26][256];
  __shared__ float plane[16 * 340];
  __shared__ float ssl[32];

  int tid = threadIdx.x;
  if (tid < 32) ssl[tid] = nss[b * 32 + tid];
  for (int r = 0; r < 26; ++r) lg[r][tid] = 0.f;

  int ty = tid >> 5, tx = tid & 31;
  int gy0 = yt * 8 - 1, gx0 = xt * 32 - 1;

  for (int zp = 0; zp < D_; ++zp) {
    __syncthreads();
    for (int i = tid; i < 16 * 340; i += 256) {
      int xx = i % 34, r = i / 34;
      int yy = r % 10, c = r / 10;
      int gy = gy0 + yy, gx = gx0 + xx;
      float v = 0.f;
      if ((unsigned)gy < (unsigned)H_ && (unsigned)gx < (unsigned)W_) {
        v = x2[(((size_t)(b * 16 + c) * D_ + zp) * H_ + gy) * W_ + gx];
        float t = fmaf(v, ssl[c * 2], ssl[c * 2 + 1]);
        v = t / (1.f + expf(-t));
      }
      plane[i] = v;
    }
    __syncthreads();
    float pm = 0.f, p0 = 0.f, pp = 0.f;  // contributions to zo = zp-1, zp, zp+1
#pragma unroll
    for (int c = 0; c < 16; ++c) {
#pragma unroll
      for (int ky = 0; ky < 3; ++ky) {
#pragma unroll
        for (int kx = 0; kx < 3; ++kx) {
          float v = plane[(c * 10 + ty + ky) * 34 + tx + kx];
          int wb = c * 27 + ky * 3 + kx;        // w3 layout [c][kz][kyx]
          pm = fmaf(v, w3[wb + 18], pm);  // kz=2 -> zo=zp-1
          p0 = fmaf(v, w3[wb + 9],  p0);  // kz=1 -> zo=zp
          pp = fmaf(v, w3[wb],      pp);  // kz=0 -> zo=zp+1
        }
      }
    }
    lg[zp][tid]     += pm;   // row zo+1
    lg[zp + 1][tid] += p0;
    lg[zp + 2][tid] += pp;
  }
  __syncthreads();

  float bias = b3[0];
  float l[24], m = -1e30f;
#pragma unroll
  for (int z = 0; z < 24; ++z) {
    l[z] = lg[z + 1][tid] + bias;
    m = fmaxf(m, l[z]);
  }
  float s = 0.f, ds = 0.f;
#pragma unroll
  for (int z = 0; z < 24; ++z) {
    float e = expf(l[z] - m);
    s += e;
    ds = fmaf(e, (float)z, ds);
  }
  float inv = 1.f / s;
  int y = yt * 8 + ty, x = xt * 32 + tx;
  out[OUT_D    + b * HW_ + y * W_ + x] = ds * inv;
  out[OUT_CONF + b * HW_ + y * W_ + x] = inv;   // max prob = exp(0)/s
}

// ============================================================
// feat head: conv2d 128->16 3x3 SAME on fL, raw output into d_out feat
// region, GN stats via atomics. Block = (b, 8x32 tile), 16 chunks of 8 ch.
// Weights from prepacked wqf (uniform scalar path).
// ============================================================
__global__ __launch_bounds__(256) void feat_conv_k(
    const float* __restrict__ fL, const float* __restrict__ wqf,
    float* __restrict__ out, float* __restrict__ stats) {
  int xt = blockIdx.x & 3;
  int yt = (blockIdx.x >> 2) & 7;
  int b  = blockIdx.x >> 5;

  __shared__ float plane[8 * 340];
  __shared__ float redS[4][8], redQ[4][8];

  int tid = threadIdx.x;
  int ty = tid >> 5, tx = tid & 31;
  int gy0 = yt * 8 - 1, gx0 = xt * 32 - 1;

  float acc[16];
#pragma unroll
  for (int o = 0; o < 16; ++o) acc[o] = 0.f;

  for (int cc = 0; cc < 16; ++cc) {
    __syncthreads();
    for (int i = tid; i < 8 * 340; i += 256) {
      int xx = i % 34, r = i / 34;
      int yy = r % 10, c = r / 10;
      int gy = gy0 + yy, gx = gx0 + xx;
      float v = 0.f;
      if ((unsigned)gy < (unsigned)H_ && (unsigned)gx < (unsigned)W_)
        v = fL[((size_t)(b * CIN + cc * 8 + c) * H_ + gy) * W_ + gx];
      plane[i] = v;
    }
    __syncthreads();
#pragma unroll
    for (int c = 0; c < 8; ++c) {
#pragma unroll
      for (int ky = 0; ky < 3; ++ky) {
#pragma unroll
        for (int kx = 0; kx < 3; ++kx) {
          float v = plane[(c * 10 + ty + ky) * 34 + tx + kx];
          const float* wp = wqf + ((cc * 8 + c) * 9 + ky * 3 + kx) * 16;
#pragma unroll
          for (int o = 0; o < 16; ++o) acc[o] = fmaf(v, wp[o], acc[o]);
        }
      }
    }
  }

  int y = yt * 8 + ty, x = xt * 32 + tx;
#pragma unroll
  for (int o = 0; o < 16; ++o)
    out[OUT_FEAT + (size_t)(b * 16 + o) * HW_ + y * W_ + x] = acc[o];

  int lane = tid & 63, wid = tid >> 6;
#pragma unroll
  for (int g = 0; g < 8; ++g) {
    float s = acc[2 * g] + acc[2 * g + 1];
    float q = fmaf(acc[2 * g], acc[2 * g], acc[2 * g + 1] * acc[2 * g + 1]);
#pragma unroll
    for (int off = 32; off > 0; off >>= 1) {
      s += __shfl_down(s, off);
      q += __shfl_down(q, off);
    }
    if (lane == 0) { redS[wid][g] = s; redQ[wid][g] = q; }
  }
  __syncthreads();
  if (tid < 16) {
    int g = tid >> 1;
    float v = (tid & 1) ? (redQ[0][g] + redQ[1][g] + redQ[2][g] + redQ[3][g])
                        : (redS[0][g] + redS[1][g] + redS[2][g] + redS[3][g]);
    atomicAdd(&stats[b * 16 + tid], v);
  }
}

// ============================================================
// finish: normalize+SiLU feat in place (float4), zero sx/sy.
// ============================================================
__global__ __launch_bounds__(256) void feat_finish_k(
    float* __restrict__ out, const float* __restrict__ ss) {
  int bid = blockIdx.x, tid = threadIdx.x;
  if (bid < 1024) {
    int idx4 = bid * 256 + tid;        // < 262144
    int bc = idx4 / 2048;              // 8192/4 per channel
    float sc = ss[bc * 2], sh = ss[bc * 2 + 1];
    float4* p = reinterpret_cast<float4*>(out + OUT_FEAT) + idx4;
    float4 v = *p;
    float t;
    t = fmaf(v.x, sc, sh); v.x = t / (1.f + expf(-t));
    t = fmaf(v.y, sc, sh); v.y = t / (1.f + expf(-t));
    t = fmaf(v.z, sc, sh); v.z = t / (1.f + expf(-t));
    t = fmaf(v.w, sc, sh); v.w = t / (1.f + expf(-t));
    *p = v;
  } else {
    int i = (bid - 1024) * 256 + tid;  // < 32768 -> covers sx+sy (131072 floats)
    float4 z = make_float4(0.f, 0.f, 0.f, 0.f);
    reinterpret_cast<float4*>(out + OUT_SX)[i] = z;
  }
}

// ============================================================
extern "C" void kernel_launch(void* const* d_in, const int* in_sizes, int n_in,
                              void* d_out, int out_size, void* d_ws, size_t ws_size,
                              hipStream_t stream) {
  const float* fL      = (const float*)d_in[0];
  const float* fR      = (const float*)d_in[1];
  const float* w1      = (const float*)d_in[2];
  const float* gn1_w   = (const float*)d_in[3];
  const float* gn1_b   = (const float*)d_in[4];
  const float* w2      = (const float*)d_in[5];
  const float* gn2_w   = (const float*)d_in[6];
  const float* gn2_b   = (const float*)d_in[7];
  const float* w3      = (const float*)d_in[8];
  const float* b3      = (const float*)d_in[9];
  const float* fh_w    = (const float*)d_in[10];
  const float* fh_gn_w = (const float*)d_in[11];
  const float* fh_gn_b = (const float*)d_in[12];
  float* out = (float*)d_out;
  float* ws  = (float*)d_ws;

  // zero the stats accumulators (ws is poisoned 0xAA before every launch)
  hipMemsetAsync(ws + ST_OFF, 0, ST_COUNT * sizeof(float), stream);

  // 0) prepack conv weights for the scalar-load path
  prepack_k<<<(WQ_TOTAL + 255) / 256, 256, 0, stream>>>(w1, w2, fh_w, ws);

  // 1) cost volume
  cost_volume_k<<<B_ * H_ * D_, 128, 0, stream>>>(fL, fR, ws + CV_OFF);

  // 2) conv1 (8->16) + gn1 stats
  conv3x3x3_k<8, false><<<B_ * D_ * 8 * 4, 256, 0, stream>>>(
      ws + CV_OFF, ws + WQ1_OFF, ws + X1_OFF, ws + GN1_STATS, nullptr);
  gn_scale_k<<<1, 128, 0, stream>>>(ws + GN1_STATS, gn1_w, gn1_b, ws + GN1_SS,
                                    1.f / 393216.f);

  // 3) conv2 (16->16) reading gn1+silu(x1) on the fly, + gn2 stats
  conv3x3x3_k<16, true><<<B_ * D_ * 8 * 4, 256, 0, stream>>>(
      ws + X1_OFF, ws + WQ2_OFF, ws + X2_OFF, ws + GN2_STATS, ws + GN1_SS);
  gn_scale_k<<<1, 128, 0, stream>>>(ws + GN2_STATS, gn2_w, gn2_b, ws + GN2_SS,
                                    1.f / 393216.f);

  // 4) conv3 (16->1) + softmax + expectation/conf, reading gn2+silu(x2)
  conv3_softmax_k<<<B_ * 8 * 4, 256, 0, stream>>>(ws + X2_OFF, w3, b3,
                                                  ws + GN2_SS, out);

  // 5) feat head conv2d + gn3 stats, then finish (normalize+silu, zero sx/sy)
  feat_conv_k<<<B_ * 8 * 4, 256, 0, stream>>>(fL, ws + WQF_OFF, out,
                                              ws + GN3_STATS);
  gn_scale_k<<<1, 128, 0, stream>>>(ws + GN3_STATS, fh_gn_w, fh_gn_b,
                                    ws + GN3_SS, 1.f / 16384.f);
  feat_finish_k<<<1152, 256, 0, stream>>>(out, ws + GN3_SS);
}

// Round 3
// 584.756 us; speedup vs baseline: 2.0952x; 2.0952x over previous
//
#include <hip/hip_runtime.h>
#include <math.h>

// ---------------- problem constants ----------------
#define B_   8
#define CIN  128
#define H_   64
#define W_   128
#define D_   24
#define HW_  (H_*W_)      // 8192

typedef _Float16 half_t;
typedef __attribute__((ext_vector_type(8))) _Float16 half8;
typedef __attribute__((ext_vector_type(4))) _Float16 half4;
typedef __attribute__((ext_vector_type(4))) float f32x4;

// ---------------- workspace layout (BYTE offsets) ----------------
// cvt: fp16 [b][d][y][x][8]   = 12,582,912 elts = 25,165,824 B at 0
// x1b: fp16 [b][z][y][x][16]  = 25,165,824 elts = 50,331,648 B
// x2b: fp16 same size
// stats floats + prepacked weights after
#define CVB   0
#define X1B   25165824
#define X2B   75497472
#define STB   125829120
// float indices within stats block (float* view of STB):
#define GN1_STATS 0      // 128 floats (b,g)*2 {sum,sumsq}
#define GN1_SS    128    // 256 floats (b,c)*2 {scale,shift}
#define GN2_STATS 384
#define GN2_SS    512
#define GN3_STATS 768
#define GN3_SS    896
#define ST_COUNT  1152
#define WQ1B  (STB + 16384)          // 3584 fp16 = 7168 B   (7 ksteps)
#define WQ2B  (WQ1B + 7168)          // 7168 fp16 = 14336 B  (14 ksteps)
#define WQFB  (WQ2B + 14336)         // 18432 fp32 = 73728 B (feat head)

// ---------------- output layout (float offsets in d_out) ----------------
#define OUT_D    0         // (B,1,H,W)  65536
#define OUT_SX   65536
#define OUT_SY   131072
#define OUT_FEAT 196608    // (B,16,H,W) 1048576
#define OUT_CONF 1245184

// ============================================================
// K0: prepack weights.
// wq1/wq2: MFMA A-fragment order [kstep][lane][j] (fp16), K-order = tap*CI + c,
//          zero-padded past K=27*CI. A[o][k]: o = lane&15, k = 32s+8*(lane>>4)+j.
// wqf: feat head fp32 [c128][kyx][o16] (unchanged from round 2).
// ============================================================
__global__ __launch_bounds__(256) void prepack_k(
    const float* __restrict__ w1, const float* __restrict__ w2,
    const float* __restrict__ fw, half_t* __restrict__ wq1,
    half_t* __restrict__ wq2, float* __restrict__ wqf) {
  int i = blockIdx.x * 256 + threadIdx.x;
  if (i < 3584) {
    int s = i >> 9, l = (i >> 3) & 63, j = i & 7;
    int o = l & 15;
    int k = s * 32 + ((l >> 4) << 3) + j;
    float v = 0.f;
    if (k < 216) {
      int tap = k >> 3, c = k & 7;
      int kz = tap / 9, kyx = tap % 9;
      v = w1[((o * 8 + c) * 3 + kz) * 9 + kyx];
    }
    wq1[i] = (half_t)v;
  } else if (i < 3584 + 7168) {
    int ii = i - 3584;
    int s = ii >> 9, l = (ii >> 3) & 63, j = ii & 7;
    int o = l & 15;
    int k = s * 32 + ((l >> 4) << 3) + j;
    float v = 0.f;
    if (k < 432) {
      int tap = k >> 4, c = k & 15;
      int kz = tap / 9, kyx = tap % 9;
      v = w2[((o * 16 + c) * 3 + kz) * 9 + kyx];
    }
    wq2[ii] = (half_t)v;
  } else if (i < 3584 + 7168 + 18432) {
    int jj = i - (3584 + 7168);
    int o = jj & 15, r = jj >> 4;
    int kyx = r % 9, c = r / 9;
    wqf[jj] = fw[(o * CIN + c) * 9 + kyx];
  }
}

// ============================================================
// K1: cost volume -> fp16 [b][d][y][x][g8]
// ============================================================
__global__ __launch_bounds__(128) void cost_volume_k(
    const float* __restrict__ fL, const float* __restrict__ fR,
    half_t* __restrict__ cvt) {
  int w  = threadIdx.x;
  int d  = blockIdx.x % D_;
  int bh = blockIdx.x / D_;
  int h  = bh & 63;
  int b  = bh >> 6;

  float acc[8];
#pragma unroll
  for (int g = 0; g < 8; ++g) acc[g] = 0.f;

  int wr = w - d;
  if (wr >= 0) {
    const float* pL = fL + (size_t)b * CIN * HW_ + h * W_ + w;
    const float* pR = fR + (size_t)b * CIN * HW_ + h * W_ + wr;
#pragma unroll
    for (int g = 0; g < 8; ++g) {
      float a = 0.f;
#pragma unroll
      for (int ci = 0; ci < 16; ++ci) {
        int c = g * 16 + ci;
        a = fmaf(pL[(size_t)c * HW_], pR[(size_t)c * HW_], a);
      }
      acc[g] = a;
    }
  }
  size_t p = (((size_t)b * D_ + d) * H_ + h) * W_ + w;
  half8 ov;
#pragma unroll
  for (int g = 0; g < 8; ++g) ov[g] = (half_t)(acc[g] * 0.0625f);
  *(half8*)(cvt + p * 8) = ov;
}

// ============================================================
// MFMA conv3d 3x3x3 CI->16, SAME. in: fp16 [b][z][y][x][CI] (pre-norm if NORM:
// gn affine + SiLU applied during LDS fill; zero-pad stays zero = reference).
// Block: 8y x 32x tile, marches 8 z-planes with rolling 3-plane LDS window.
// 4 waves; wave w owns rows {2w,2w+1} = 4 MFMA n-tiles of 16 pixels.
// Weights held in VGPRs (A-fragments). Output fp16 [b][z][y][x][16] pre-norm
// + GN stats (fp32 acc) via shuffle reduce + atomics.
// ============================================================
template <int CI, bool NORM>
__global__ __launch_bounds__(256, 2) void conv_mfma_k(
    const half_t* __restrict__ in, const half_t* __restrict__ wq,
    half_t* __restrict__ outp, float* __restrict__ stats,
    const float* __restrict__ nss) {
  constexpr int KS    = (CI == 16) ? 14 : 7;   // k-steps of 32
  constexpr int PITCH = (CI == 16) ? 24 : 8;   // halfwords per pixel in LDS
  constexpr int TPS   = 32 / CI;               // taps per k-step

  __shared__ half_t act[3 * 340 * PITCH];      // [slot][10*34 pix][PITCH]
  __shared__ float redS[4][16], redQ[4][16];

  int tid = threadIdx.x;
  int l = tid & 63, w = tid >> 6;
  int bid = blockIdx.x;
  int xt = bid & 3, yt = (bid >> 2) & 7;
  int r5 = bid >> 5;
  int zc = r5 % 3, b = r5 / 3;
  int z0 = zc * 8;
  int y0 = yt * 8, x0 = xt * 32;

  // ---- weight A-fragments into registers ----
  half8 wfrag[KS];
#pragma unroll
  for (int s = 0; s < KS; ++s)
    wfrag[s] = *(const half8*)(wq + (s * 64 + l) * 8);

  // ---- per-thread GN scale/shift for its chunk parity ----
  float sc[8], sh[8];
  if (NORM) {
    int c0 = (tid & 1) * 8;
#pragma unroll
    for (int j = 0; j < 8; ++j) {
      sc[j] = nss[b * 32 + (c0 + j) * 2];
      sh[j] = nss[b * 32 + (c0 + j) * 2 + 1];
    }
  }

  // ---- fill one z-plane into LDS slot ----
  auto fill = [&](int zi, int slot) {
    if (CI == 16) {
      for (int u = tid; u < 680; u += 256) {
        int chunk = u & 1, pix = u >> 1;
        int yy = pix / 34, xx = pix - yy * 34;
        int gy = y0 - 1 + yy, gx = x0 - 1 + xx;
        half8 v = {0, 0, 0, 0, 0, 0, 0, 0};
        if ((unsigned)zi < 24u && (unsigned)gy < 64u && (unsigned)gx < 128u) {
          half8 rr = *(const half8*)(in +
              ((((size_t)b * D_ + zi) * H_ + gy) * W_ + gx) * 16 + chunk * 8);
          if (NORM) {
#pragma unroll
            for (int j = 0; j < 8; ++j) {
              float t = fmaf((float)rr[j], sc[j], sh[j]);
              v[j] = (half_t)(t / (1.f + __expf(-t)));
            }
          } else {
            v = rr;
          }
        }
        *(half8*)(act + (slot * 340 + pix) * PITCH + chunk * 8) = v;
      }
    } else {
      for (int u = tid; u < 340; u += 256) {
        int yy = u / 34, xx = u - yy * 34;
        int gy = y0 - 1 + yy, gx = x0 - 1 + xx;
        half8 v = {0, 0, 0, 0, 0, 0, 0, 0};
        if ((unsigned)zi < 24u && (unsigned)gy < 64u && (unsigned)gx < 128u)
          v = *(const half8*)(in +
              ((((size_t)b * D_ + zi) * H_ + gy) * W_ + gx) * 8);
        *(half8*)(act + (slot * 340 + u) * PITCH) = v;
      }
    }
  };

  // ---- per-lane compute constants ----
  int q = l >> 4, n = l & 15;
  int chalf  = (CI == 16) ? (q & 1) * 8 : 0;
  int tapadd = (CI == 16) ? (q >> 1) : q;
  int ntoff[4];
#pragma unroll
  for (int nt = 0; nt < 4; ++nt)
    ntoff[nt] = ((2 * w + (nt >> 1)) * 34 + (nt & 1) * 16) * PITCH;

  float sacc[4] = {0.f, 0.f, 0.f, 0.f}, qacc[4] = {0.f, 0.f, 0.f, 0.f};

  // ---- prologue fills ----
  fill(z0 - 1, z0 % 3);           // slot(P) = (P+1)%3
  fill(z0, (z0 + 1) % 3);

  for (int z = z0; z < z0 + 8; ++z) {
    fill(z + 1, (z + 2) % 3);
    __syncthreads();
    int zm3 = z % 3;

    f32x4 accv[4];
#pragma unroll
    for (int nt = 0; nt < 4; ++nt) accv[nt] = (f32x4){0.f, 0.f, 0.f, 0.f};

#pragma unroll
    for (int s = 0; s < KS; ++s) {
      int tap = TPS * s + tapadd;
      tap = tap > 26 ? 26 : tap;          // pad taps: weights are zero
      int kz = (tap * 57) >> 9;           // /9 for tap<=26
      int t9 = tap - kz * 9;
      int ky = (t9 * 11) >> 5;            // /3 for t9<=8
      int kx = t9 - ky * 3;
      int sl = zm3 + kz; if (sl >= 3) sl -= 3;
      int base = (sl * 340 + ky * 34 + kx + n) * PITCH + chalf;
#pragma unroll
      for (int nt = 0; nt < 4; ++nt) {
        half8 bf = *(const half8*)(act + base + ntoff[nt]);
        accv[nt] =
            __builtin_amdgcn_mfma_f32_16x16x32_f16(wfrag[s], bf, accv[nt], 0, 0, 0);
      }
    }

    // epilogue: store fp16 pre-norm output + accumulate stats
#pragma unroll
    for (int nt = 0; nt < 4; ++nt) {
      int ygl = y0 + 2 * w + (nt >> 1);
      int xgl = x0 + (nt & 1) * 16 + n;
      half4 o;
#pragma unroll
      for (int r = 0; r < 4; ++r) {
        float v = accv[nt][r];
        o[r] = (half_t)v;
        sacc[r] += v;
        qacc[r] = fmaf(v, v, qacc[r]);
      }
      *(half4*)(outp + ((((size_t)b * D_ + z) * H_ + ygl) * W_ + xgl) * 16 +
                q * 4) = o;
    }
    __syncthreads();
  }

  // ---- stats reduce: lane holds channels q*4+r ----
#pragma unroll
  for (int r = 0; r < 4; ++r) {
#pragma unroll
    for (int m = 1; m < 16; m <<= 1) {
      sacc[r] += __shfl_xor(sacc[r], m);
      qacc[r] += __shfl_xor(qacc[r], m);
    }
  }
  if (n == 0) {
#pragma unroll
    for (int r = 0; r < 4; ++r) {
      redS[w][q * 4 + r] = sacc[r];
      redQ[w][q * 4 + r] = qacc[r];
    }
  }
  __syncthreads();
  if (tid < 16) {
    int g = tid >> 1;
    float v = 0.f;
    if (tid & 1) {
      for (int ww = 0; ww < 4; ++ww) v += redQ[ww][2 * g] + redQ[ww][2 * g + 1];
    } else {
      for (int ww = 0; ww < 4; ++ww) v += redS[ww][2 * g] + redS[ww][2 * g + 1];
    }
    atomicAdd(&stats[b * 16 + tid], v);
  }
}

// ============================================================
// stats -> per (b,c) scale/shift:  xhat = x*scale + shift
// ============================================================
__global__ __launch_bounds__(128) void gn_scale_k(
    const float* __restrict__ stats, const float* __restrict__ gw,
    const float* __restrict__ gb, float* __restrict__ ss, float inv_count) {
  int i = threadIdx.x;  // b*16+c
  if (i < 128) {
    int c = i & 15, g = c >> 1, b = i >> 4;
    float sum = stats[(b * 8 + g) * 2];
    float sq  = stats[(b * 8 + g) * 2 + 1];
    float mean = sum * inv_count;
    float var  = sq * inv_count - mean * mean;
    float rstd = rsqrtf(var + 1e-5f);
    float scv = gw[c] * rstd;
    ss[i * 2] = scv;
    ss[i * 2 + 1] = gb[c] - mean * scv;
  }
}

// ============================================================
// conv3d 16->1 (+bias) fused with softmax over D, expectation + max-prob.
// x2: fp16 [b][z][y][x][16] pre-norm; gn2 affine + SiLU on LDS fill.
// ============================================================
__global__ __launch_bounds__(256) void conv3_softmax_k(
    const half_t* __restrict__ x2, const float* __restrict__ w3,
    const float* __restrict__ b3, const float* __restrict__ nss,
    float* __restrict__ out) {
  int xt = blockIdx.x & 3;
  int yt = (blockIdx.x >> 2) & 7;
  int b  = blockIdx.x >> 5;

  __shared__ float lg[26][256];
  __shared__ float plane[16 * 340];   // [c][10*34]

  int tid = threadIdx.x;
  for (int r = 0; r < 26; ++r) lg[r][tid] = 0.f;

  // per-thread gn2 scale/shift for its chunk parity
  float sc[8], sh[8];
  {
    int c0 = (tid & 1) * 8;
#pragma unroll
    for (int j = 0; j < 8; ++j) {
      sc[j] = nss[b * 32 + (c0 + j) * 2];
      sh[j] = nss[b * 32 + (c0 + j) * 2 + 1];
    }
  }

  int ty = tid >> 5, tx = tid & 31;
  int gy0 = yt * 8 - 1, gx0 = xt * 32 - 1;

  for (int zp = 0; zp < D_; ++zp) {
    __syncthreads();
    for (int u = tid; u < 680; u += 256) {
      int chunk = u & 1, pix = u >> 1;
      int yy = pix / 34, xx = pix - yy * 34;
      int gy = gy0 + yy, gx = gx0 + xx;
      int c0 = chunk * 8;
      if ((unsigned)gy < 64u && (unsigned)gx < 128u) {
        half8 rr = *(const half8*)(x2 +
            ((((size_t)b * D_ + zp) * H_ + gy) * W_ + gx) * 16 + c0);
#pragma unroll
        for (int j = 0; j < 8; ++j) {
          float t = fmaf((float)rr[j], sc[j], sh[j]);
          plane[(c0 + j) * 340 + pix] = t / (1.f + expf(-t));
        }
      } else {
#pragma unroll
        for (int j = 0; j < 8; ++j) plane[(c0 + j) * 340 + pix] = 0.f;
      }
    }
    __syncthreads();
    float pm = 0.f, p0 = 0.f, pp = 0.f;  // -> zo = zp-1, zp, zp+1
#pragma unroll
    for (int c = 0; c < 16; ++c) {
#pragma unroll
      for (int ky = 0; ky < 3; ++ky) {
#pragma unroll
        for (int kx = 0; kx < 3; ++kx) {
          float v = plane[c * 340 + (ty + ky) * 34 + tx + kx];
          int wb = c * 27 + ky * 3 + kx;   // w3 layout [c][kz][kyx]
          pm = fmaf(v, w3[wb + 18], pm);
          p0 = fmaf(v, w3[wb + 9],  p0);
          pp = fmaf(v, w3[wb],      pp);
        }
      }
    }
    lg[zp][tid]     += pm;
    lg[zp + 1][tid] += p0;
    lg[zp + 2][tid] += pp;
  }
  __syncthreads();

  float bias = b3[0];
  float lv[24], m = -1e30f;
#pragma unroll
  for (int z = 0; z < 24; ++z) {
    lv[z] = lg[z + 1][tid] + bias;
    m = fmaxf(m, lv[z]);
  }
  float s = 0.f, ds = 0.f;
#pragma unroll
  for (int z = 0; z < 24; ++z) {
    float e = expf(lv[z] - m);
    s += e;
    ds = fmaf(e, (float)z, ds);
  }
  float inv = 1.f / s;
  int y = yt * 8 + ty, x = xt * 32 + tx;
  out[OUT_D    + b * HW_ + y * W_ + x] = ds * inv;
  out[OUT_CONF + b * HW_ + y * W_ + x] = inv;
}

// ============================================================
// feat head: conv2d 128->16 3x3 SAME on fL (fp32 VALU), + gn3 stats.
// ============================================================
__global__ __launch_bounds__(256) void feat_conv_k(
    const float* __restrict__ fL, const float* __restrict__ wqf,
    float* __restrict__ out, float* __restrict__ stats) {
  int xt = blockIdx.x & 3;
  int yt = (blockIdx.x >> 2) & 7;
  int b  = blockIdx.x >> 5;

  __shared__ float plane[8 * 340];
  __shared__ float redS[4][8], redQ[4][8];

  int tid = threadIdx.x;
  int ty = tid >> 5, tx = tid & 31;
  int gy0 = yt * 8 - 1, gx0 = xt * 32 - 1;

  float acc[16];
#pragma unroll
  for (int o = 0; o < 16; ++o) acc[o] = 0.f;

  for (int cc = 0; cc < 16; ++cc) {
    __syncthreads();
    for (int i = tid; i < 8 * 340; i += 256) {
      int xx = i % 34, r = i / 34;
      int yy = r % 10, c = r / 10;
      int gy = gy0 + yy, gx = gx0 + xx;
      float v = 0.f;
      if ((unsigned)gy < (unsigned)H_ && (unsigned)gx < (unsigned)W_)
        v = fL[((size_t)(b * CIN + cc * 8 + c) * H_ + gy) * W_ + gx];
      plane[i] = v;
    }
    __syncthreads();
#pragma unroll
    for (int c = 0; c < 8; ++c) {
#pragma unroll
      for (int ky = 0; ky < 3; ++ky) {
#pragma unroll
        for (int kx = 0; kx < 3; ++kx) {
          float v = plane[(c * 10 + ty + ky) * 34 + tx + kx];
          const float* wp = wqf + ((cc * 8 + c) * 9 + ky * 3 + kx) * 16;
#pragma unroll
          for (int o = 0; o < 16; ++o) acc[o] = fmaf(v, wp[o], acc[o]);
        }
      }
    }
  }

  int y = yt * 8 + ty, x = xt * 32 + tx;
#pragma unroll
  for (int o = 0; o < 16; ++o)
    out[OUT_FEAT + (size_t)(b * 16 + o) * HW_ + y * W_ + x] = acc[o];

  int lane = tid & 63, wid = tid >> 6;
#pragma unroll
  for (int g = 0; g < 8; ++g) {
    float s = acc[2 * g] + acc[2 * g + 1];
    float qq = fmaf(acc[2 * g], acc[2 * g], acc[2 * g + 1] * acc[2 * g + 1]);
#pragma unroll
    for (int off = 32; off > 0; off >>= 1) {
      s += __shfl_down(s, off);
      qq += __shfl_down(qq, off);
    }
    if (lane == 0) { redS[wid][g] = s; redQ[wid][g] = qq; }
  }
  __syncthreads();
  if (tid < 16) {
    int g = tid >> 1;
    float v = (tid & 1) ? (redQ[0][g] + redQ[1][g] + redQ[2][g] + redQ[3][g])
                        : (redS[0][g] + redS[1][g] + redS[2][g] + redS[3][g]);
    atomicAdd(&stats[b * 16 + tid], v);
  }
}

// ============================================================
// finish: normalize+SiLU feat in place (float4), zero sx/sy.
// ============================================================
__global__ __launch_bounds__(256) void feat_finish_k(
    float* __restrict__ out, const float* __restrict__ ss) {
  int bid = blockIdx.x, tid = threadIdx.x;
  if (bid < 1024) {
    int idx4 = bid * 256 + tid;
    int bc = idx4 / 2048;
    float scv = ss[bc * 2], shv = ss[bc * 2 + 1];
    float4* p = reinterpret_cast<float4*>(out + OUT_FEAT) + idx4;
    float4 v = *p;
    float t;
    t = fmaf(v.x, scv, shv); v.x = t / (1.f + expf(-t));
    t = fmaf(v.y, scv, shv); v.y = t / (1.f + expf(-t));
    t = fmaf(v.z, scv, shv); v.z = t / (1.f + expf(-t));
    t = fmaf(v.w, scv, shv); v.w = t / (1.f + expf(-t));
    *p = v;
  } else {
    int i = (bid - 1024) * 256 + tid;
    float4 z = make_float4(0.f, 0.f, 0.f, 0.f);
    reinterpret_cast<float4*>(out + OUT_SX)[i] = z;
  }
}

// ============================================================
extern "C" void kernel_launch(void* const* d_in, const int* in_sizes, int n_in,
                              void* d_out, int out_size, void* d_ws, size_t ws_size,
                              hipStream_t stream) {
  const float* fL      = (const float*)d_in[0];
  const float* fR      = (const float*)d_in[1];
  const float* w1      = (const float*)d_in[2];
  const float* gn1_w   = (const float*)d_in[3];
  const float* gn1_b   = (const float*)d_in[4];
  const float* w2      = (const float*)d_in[5];
  const float* gn2_w   = (const float*)d_in[6];
  const float* gn2_b   = (const float*)d_in[7];
  const float* w3      = (const float*)d_in[8];
  const float* b3      = (const float*)d_in[9];
  const float* fh_w    = (const float*)d_in[10];
  const float* fh_gn_w = (const float*)d_in[11];
  const float* fh_gn_b = (const float*)d_in[12];
  float* out = (float*)d_out;
  char*  W   = (char*)d_ws;

  half_t* cvt = (half_t*)(W + CVB);
  half_t* x1b = (half_t*)(W + X1B);
  half_t* x2b = (half_t*)(W + X2B);
  float*  stF = (float*)(W + STB);
  half_t* wq1 = (half_t*)(W + WQ1B);
  half_t* wq2 = (half_t*)(W + WQ2B);
  float*  wqf = (float*)(W + WQFB);

  hipMemsetAsync(stF, 0, ST_COUNT * sizeof(float), stream);

  prepack_k<<<114, 256, 0, stream>>>(w1, w2, fh_w, wq1, wq2, wqf);

  cost_volume_k<<<B_ * H_ * D_, 128, 0, stream>>>(fL, fR, cvt);

  conv_mfma_k<8, false><<<768, 256, 0, stream>>>(
      cvt, wq1, x1b, stF + GN1_STATS, nullptr);
  gn_scale_k<<<1, 128, 0, stream>>>(stF + GN1_STATS, gn1_w, gn1_b,
                                    stF + GN1_SS, 1.f / 393216.f);

  conv_mfma_k<16, true><<<768, 256, 0, stream>>>(
      x1b, wq2, x2b, stF + GN2_STATS, stF + GN1_SS);
  gn_scale_k<<<1, 128, 0, stream>>>(stF + GN2_STATS, gn2_w, gn2_b,
                                    stF + GN2_SS, 1.f / 393216.f);

  conv3_softmax_k<<<B_ * 8 * 4, 256, 0, stream>>>(x2b, w3, b3,
                                                  stF + GN2_SS, out);

  feat_conv_k<<<B_ * 8 * 4, 256, 0, stream>>>(fL, wqf, out, stF + GN3_STATS);
  gn_scale_k<<<1, 128, 0, stream>>>(stF + GN3_STATS, fh_gn_w, fh_gn_b,
                                    stF + GN3_SS, 1.f / 16384.f);
  feat_finish_k<<<1152, 256, 0, stream>>>(out, stF + GN3_SS);
}

// Round 6
// 437.092 us; speedup vs baseline: 2.8031x; 1.3378x over previous
//
#include <hip/hip_runtime.h>
#include <math.h>

// ---------------- problem constants ----------------
#define B_   8
#define CIN  128
#define H_   64
#define W_   128
#define D_   24
#define HW_  (H_*W_)      // 8192

typedef _Float16 half_t;
typedef __attribute__((ext_vector_type(8))) _Float16 half8;
typedef __attribute__((ext_vector_type(4))) _Float16 half4;
typedef __attribute__((ext_vector_type(4))) float f32x4;

// ---------------- workspace layout (BYTE offsets) ----------------
#define CVB   0
#define X1B   25165824
#define X2B   75497472
#define STB   125829120
// float indices within stats block (float* view of STB):
#define GN1_STATS 0      // 128 floats (b,g)*2 {sum,sumsq}
#define GN1_SS    128    // 256 floats (b,c)*2 {scale,shift}
#define GN2_STATS 384
#define GN2_SS    512
#define GN3_STATS 768
#define GN3_SS    896
#define ST_COUNT  1152
#define WQ1B  (STB + 16384)          // 3584 fp16 = 7168 B   (7 ksteps)
#define WQ2B  (WQ1B + 7168)          // 7168 fp16 = 14336 B  (14 ksteps)
#define WQFB  (WQ2B + 14336)         // 18432 fp16 = 36864 B (feat, 4cc x 9s)

// ---------------- output layout (float offsets in d_out) ----------------
#define OUT_D    0         // (B,1,H,W)  65536
#define OUT_SX   65536
#define OUT_SY   131072
#define OUT_FEAT 196608    // (B,16,H,W) 1048576
#define OUT_CONF 1245184

// ============================================================
// K0: prepack weights into MFMA A-fragment order (fp16).
// A[m=o][k]: lane l -> m = l&15, k = ks*32 + (l>>4)*8 + j.
// wq1: K-order tap*8+c  (7 ksteps, zero-padded past 216)
// wq2: K-order tap*16+c (14 ksteps, zero-padded past 432)
// wqf2: per 32-ch chunk cc, K-order tap-major: step s = tap, k-local = c32.
// ============================================================
__global__ __launch_bounds__(256) void prepack_k(
    const float* __restrict__ w1, const float* __restrict__ w2,
    const float* __restrict__ fw, half_t* __restrict__ wq1,
    half_t* __restrict__ wq2, half_t* __restrict__ wqf2) {
  int i = blockIdx.x * 256 + threadIdx.x;
  if (i < 3584) {
    int s = i >> 9, l = (i >> 3) & 63, j = i & 7;
    int o = l & 15;
    int k = s * 32 + ((l >> 4) << 3) + j;
    float v = 0.f;
    if (k < 216) {
      int tap = k >> 3, c = k & 7;
      int kz = tap / 9, kyx = tap % 9;
      v = w1[((o * 8 + c) * 3 + kz) * 9 + kyx];
    }
    wq1[i] = (half_t)v;
  } else if (i < 3584 + 7168) {
    int ii = i - 3584;
    int s = ii >> 9, l = (ii >> 3) & 63, j = ii & 7;
    int o = l & 15;
    int k = s * 32 + ((l >> 4) << 3) + j;
    float v = 0.f;
    if (k < 432) {
      int tap = k >> 4, c = k & 15;
      int kz = tap / 9, kyx = tap % 9;
      v = w2[((o * 16 + c) * 3 + kz) * 9 + kyx];
    }
    wq2[ii] = (half_t)v;
  } else if (i < 3584 + 7168 + 18432) {
    int jj = i - (3584 + 7168);
    int cc = jj / 4608, rem = jj % 4608;
    int s = rem >> 9, l = (rem >> 3) & 63, j = rem & 7;
    int o = l & 15;
    int c = cc * 32 + ((l >> 4) << 3) + j;
    wqf2[jj] = (half_t)fw[(o * CIN + c) * 9 + s];   // s = ky*3+kx
  }
}

// ============================================================
// K1: cost volume -> fp16 [b][d][y][x][g8]
// ============================================================
__global__ __launch_bounds__(128) void cost_volume_k(
    const float* __restrict__ fL, const float* __restrict__ fR,
    half_t* __restrict__ cvt) {
  int w  = threadIdx.x;
  int d  = blockIdx.x % D_;
  int bh = blockIdx.x / D_;
  int h  = bh & 63;
  int b  = bh >> 6;

  float acc[8];
#pragma unroll
  for (int g = 0; g < 8; ++g) acc[g] = 0.f;

  int wr = w - d;
  if (wr >= 0) {
    const float* pL = fL + (size_t)b * CIN * HW_ + h * W_ + w;
    const float* pR = fR + (size_t)b * CIN * HW_ + h * W_ + wr;
#pragma unroll
    for (int g = 0; g < 8; ++g) {
      float a = 0.f;
#pragma unroll
      for (int ci = 0; ci < 16; ++ci) {
        int c = g * 16 + ci;
        a = fmaf(pL[(size_t)c * HW_], pR[(size_t)c * HW_], a);
      }
      acc[g] = a;
    }
  }
  size_t p = (((size_t)b * D_ + d) * H_ + h) * W_ + w;
  half8 ov;
#pragma unroll
  for (int g = 0; g < 8; ++g) ov[g] = (half_t)(acc[g] * 0.0625f);
  *(half8*)(cvt + p * 8) = ov;
}

// ============================================================
// MFMA conv3d 3x3x3 CI->16 (unchanged from round 3, verified).
// ============================================================
template <int CI, bool NORM>
__global__ __launch_bounds__(256, 2) void conv_mfma_k(
    const half_t* __restrict__ in, const half_t* __restrict__ wq,
    half_t* __restrict__ outp, float* __restrict__ stats,
    const float* __restrict__ nss) {
  constexpr int KS    = (CI == 16) ? 14 : 7;
  constexpr int PITCH = (CI == 16) ? 24 : 8;
  constexpr int TPS   = 32 / CI;

  __shared__ half_t act[3 * 340 * PITCH];
  __shared__ float redS[4][16], redQ[4][16];

  int tid = threadIdx.x;
  int l = tid & 63, w = tid >> 6;
  int bid = blockIdx.x;
  int xt = bid & 3, yt = (bid >> 2) & 7;
  int r5 = bid >> 5;
  int zc = r5 % 3, b = r5 / 3;
  int z0 = zc * 8;
  int y0 = yt * 8, x0 = xt * 32;

  half8 wfrag[KS];
#pragma unroll
  for (int s = 0; s < KS; ++s)
    wfrag[s] = *(const half8*)(wq + (s * 64 + l) * 8);

  float sc[8], sh[8];
  if (NORM) {
    int c0 = (tid & 1) * 8;
#pragma unroll
    for (int j = 0; j < 8; ++j) {
      sc[j] = nss[b * 32 + (c0 + j) * 2];
      sh[j] = nss[b * 32 + (c0 + j) * 2 + 1];
    }
  }

  auto fill = [&](int zi, int slot) {
    if (CI == 16) {
      for (int u = tid; u < 680; u += 256) {
        int chunk = u & 1, pix = u >> 1;
        int yy = pix / 34, xx = pix - yy * 34;
        int gy = y0 - 1 + yy, gx = x0 - 1 + xx;
        half8 v = {0, 0, 0, 0, 0, 0, 0, 0};
        if ((unsigned)zi < 24u && (unsigned)gy < 64u && (unsigned)gx < 128u) {
          half8 rr = *(const half8*)(in +
              ((((size_t)b * D_ + zi) * H_ + gy) * W_ + gx) * 16 + chunk * 8);
          if (NORM) {
#pragma unroll
            for (int j = 0; j < 8; ++j) {
              float t = fmaf((float)rr[j], sc[j], sh[j]);
              v[j] = (half_t)(t / (1.f + __expf(-t)));
            }
          } else {
            v = rr;
          }
        }
        *(half8*)(act + (slot * 340 + pix) * PITCH + chunk * 8) = v;
      }
    } else {
      for (int u = tid; u < 340; u += 256) {
        int yy = u / 34, xx = u - yy * 34;
        int gy = y0 - 1 + yy, gx = x0 - 1 + xx;
        half8 v = {0, 0, 0, 0, 0, 0, 0, 0};
        if ((unsigned)zi < 24u && (unsigned)gy < 64u && (unsigned)gx < 128u)
          v = *(const half8*)(in +
              ((((size_t)b * D_ + zi) * H_ + gy) * W_ + gx) * 8);
        *(half8*)(act + (slot * 340 + u) * PITCH) = v;
      }
    }
  };

  int q = l >> 4, n = l & 15;
  int chalf  = (CI == 16) ? (q & 1) * 8 : 0;
  int tapadd = (CI == 16) ? (q >> 1) : q;
  int ntoff[4];
#pragma unroll
  for (int nt = 0; nt < 4; ++nt)
    ntoff[nt] = ((2 * w + (nt >> 1)) * 34 + (nt & 1) * 16) * PITCH;

  float sacc[4] = {0.f, 0.f, 0.f, 0.f}, qacc[4] = {0.f, 0.f, 0.f, 0.f};

  fill(z0 - 1, z0 % 3);
  fill(z0, (z0 + 1) % 3);

  for (int z = z0; z < z0 + 8; ++z) {
    fill(z + 1, (z + 2) % 3);
    __syncthreads();
    int zm3 = z % 3;

    f32x4 accv[4];
#pragma unroll
    for (int nt = 0; nt < 4; ++nt) accv[nt] = (f32x4){0.f, 0.f, 0.f, 0.f};

#pragma unroll
    for (int s = 0; s < KS; ++s) {
      int tap = TPS * s + tapadd;
      tap = tap > 26 ? 26 : tap;
      int kz = (tap * 57) >> 9;
      int t9 = tap - kz * 9;
      int ky = (t9 * 11) >> 5;
      int kx = t9 - ky * 3;
      int sl = zm3 + kz; if (sl >= 3) sl -= 3;
      int base = (sl * 340 + ky * 34 + kx + n) * PITCH + chalf;
#pragma unroll
      for (int nt = 0; nt < 4; ++nt) {
        half8 bf = *(const half8*)(act + base + ntoff[nt]);
        accv[nt] =
            __builtin_amdgcn_mfma_f32_16x16x32_f16(wfrag[s], bf, accv[nt], 0, 0, 0);
      }
    }

#pragma unroll
    for (int nt = 0; nt < 4; ++nt) {
      int ygl = y0 + 2 * w + (nt >> 1);
      int xgl = x0 + (nt & 1) * 16 + n;
      half4 o;
#pragma unroll
      for (int r = 0; r < 4; ++r) {
        float v = accv[nt][r];
        o[r] = (half_t)v;
        sacc[r] += v;
        qacc[r] = fmaf(v, v, qacc[r]);
      }
      *(half4*)(outp + ((((size_t)b * D_ + z) * H_ + ygl) * W_ + xgl) * 16 +
                q * 4) = o;
    }
    __syncthreads();
  }

#pragma unroll
  for (int r = 0; r < 4; ++r) {
#pragma unroll
    for (int m = 1; m < 16; m <<= 1) {
      sacc[r] += __shfl_xor(sacc[r], m);
      qacc[r] += __shfl_xor(qacc[r], m);
    }
  }
  if (n == 0) {
#pragma unroll
    for (int r = 0; r < 4; ++r) {
      redS[w][q * 4 + r] = sacc[r];
      redQ[w][q * 4 + r] = qacc[r];
    }
  }
  __syncthreads();
  if (tid < 16) {
    int g = tid >> 1;
    float v = 0.f;
    if (tid & 1) {
      for (int ww = 0; ww < 4; ++ww) v += redQ[ww][2 * g] + redQ[ww][2 * g + 1];
    } else {
      for (int ww = 0; ww < 4; ++ww) v += redS[ww][2 * g] + redS[ww][2 * g + 1];
    }
    atomicAdd(&stats[b * 16 + tid], v);
  }
}

// ============================================================
// stats -> per (b,c) scale/shift
// ============================================================
__global__ __launch_bounds__(128) void gn_scale_k(
    const float* __restrict__ stats, const float* __restrict__ gw,
    const float* __restrict__ gb, float* __restrict__ ss, float inv_count) {
  int i = threadIdx.x;
  if (i < 128) {
    int c = i & 15, g = c >> 1, b = i >> 4;
    float sum = stats[(b * 8 + g) * 2];
    float sq  = stats[(b * 8 + g) * 2 + 1];
    float mean = sum * inv_count;
    float var  = sq * inv_count - mean * mean;
    float rstd = rsqrtf(var + 1e-5f);
    float scv = gw[c] * rstd;
    ss[i * 2] = scv;
    ss[i * 2 + 1] = gb[c] - mean * scv;
  }
}

// ============================================================
// conv3d 16->1 + softmax over D (unchanged from round 3, verified).
// ============================================================
__global__ __launch_bounds__(256) void conv3_softmax_k(
    const half_t* __restrict__ x2, const float* __restrict__ w3,
    const float* __restrict__ b3, const float* __restrict__ nss,
    float* __restrict__ out) {
  int xt = blockIdx.x & 3;
  int yt = (blockIdx.x >> 2) & 7;
  int b  = blockIdx.x >> 5;

  __shared__ float lg[26][256];
  __shared__ float plane[16 * 340];

  int tid = threadIdx.x;
  for (int r = 0; r < 26; ++r) lg[r][tid] = 0.f;

  float sc[8], sh[8];
  {
    int c0 = (tid & 1) * 8;
#pragma unroll
    for (int j = 0; j < 8; ++j) {
      sc[j] = nss[b * 32 + (c0 + j) * 2];
      sh[j] = nss[b * 32 + (c0 + j) * 2 + 1];
    }
  }

  int ty = tid >> 5, tx = tid & 31;
  int gy0 = yt * 8 - 1, gx0 = xt * 32 - 1;

  for (int zp = 0; zp < D_; ++zp) {
    __syncthreads();
    for (int u = tid; u < 680; u += 256) {
      int chunk = u & 1, pix = u >> 1;
      int yy = pix / 34, xx = pix - yy * 34;
      int gy = gy0 + yy, gx = gx0 + xx;
      int c0 = chunk * 8;
      if ((unsigned)gy < 64u && (unsigned)gx < 128u) {
        half8 rr = *(const half8*)(x2 +
            ((((size_t)b * D_ + zp) * H_ + gy) * W_ + gx) * 16 + c0);
#pragma unroll
        for (int j = 0; j < 8; ++j) {
          float t = fmaf((float)rr[j], sc[j], sh[j]);
          plane[(c0 + j) * 340 + pix] = t / (1.f + expf(-t));
        }
      } else {
#pragma unroll
        for (int j = 0; j < 8; ++j) plane[(c0 + j) * 340 + pix] = 0.f;
      }
    }
    __syncthreads();
    float pm = 0.f, p0 = 0.f, pp = 0.f;
#pragma unroll
    for (int c = 0; c < 16; ++c) {
#pragma unroll
      for (int ky = 0; ky < 3; ++ky) {
#pragma unroll
        for (int kx = 0; kx < 3; ++kx) {
          float v = plane[c * 340 + (ty + ky) * 34 + tx + kx];
          int wb = c * 27 + ky * 3 + kx;
          pm = fmaf(v, w3[wb + 18], pm);
          p0 = fmaf(v, w3[wb + 9],  p0);
          pp = fmaf(v, w3[wb],      pp);
        }
      }
    }
    lg[zp][tid]     += pm;
    lg[zp + 1][tid] += p0;
    lg[zp + 2][tid] += pp;
  }
  __syncthreads();

  float bias = b3[0];
  float lv[24], m = -1e30f;
#pragma unroll
  for (int z = 0; z < 24; ++z) {
    lv[z] = lg[z + 1][tid] + bias;
    m = fmaxf(m, lv[z]);
  }
  float s = 0.f, ds = 0.f;
#pragma unroll
  for (int z = 0; z < 24; ++z) {
    float e = expf(lv[z] - m);
    s += e;
    ds = fmaf(e, (float)z, ds);
  }
  float inv = 1.f / s;
  int y = yt * 8 + ty, x = xt * 32 + tx;
  out[OUT_D    + b * HW_ + y * W_ + x] = ds * inv;
  out[OUT_CONF + b * HW_ + y * W_ + x] = inv;
}

// ============================================================
// feat head: MFMA conv2d 128->16 3x3 SAME on fL (fp32 in, fp16 MFMA).
// Block = (b, 8y x 32x tile), 4 chunks of 32 input channels, 9 taps each
// (K=32 per MFMA step, no padding). LDS act pitch = 40 halfwords (80 B):
// 16B-aligned b128 reads, word-stride 20 -> conflict-free bank spread.
// Raw fp32 conv output to OUT_FEAT + gn3 stats.
// ============================================================
__global__ __launch_bounds__(256, 2) void feat_mfma_k(
    const float* __restrict__ fL, const half_t* __restrict__ wqf2,
    float* __restrict__ out, float* __restrict__ stats) {
  constexpr int PITCH = 40;

  __shared__ half_t act[340 * PITCH];   // 27200 B
  __shared__ float redS[4][16], redQ[4][16];

  int tid = threadIdx.x;
  int l = tid & 63, w = tid >> 6;
  int xt = blockIdx.x & 3;
  int yt = (blockIdx.x >> 2) & 7;
  int b  = blockIdx.x >> 5;
  int y0 = yt * 8, x0 = xt * 32;

  int q = l >> 4, n = l & 15;
  int ntoff[4];
#pragma unroll
  for (int nt = 0; nt < 4; ++nt)
    ntoff[nt] = ((2 * w + (nt >> 1)) * 34 + (nt & 1) * 16) * PITCH;

  f32x4 accv[4];
#pragma unroll
  for (int nt = 0; nt < 4; ++nt) accv[nt] = (f32x4){0.f, 0.f, 0.f, 0.f};

  for (int cc = 0; cc < 4; ++cc) {
    // A-fragments for this channel chunk: 9 taps
    half8 wfrag[9];
#pragma unroll
    for (int s = 0; s < 9; ++s)
      wfrag[s] = *(const half8*)(wqf2 + ((cc * 9 + s) * 64 + l) * 8);

    __syncthreads();
    // fill: 340 pixels x 32 channels, fp32 -> fp16
    for (int u = tid; u < 1360; u += 256) {
      int qq = u & 3, pix = u >> 2;
      int yy = pix / 34, xx = pix - yy * 34;
      int gy = y0 - 1 + yy, gx = x0 - 1 + xx;
      half8 v = {0, 0, 0, 0, 0, 0, 0, 0};
      if ((unsigned)gy < 64u && (unsigned)gx < 128u) {
        const float* src = fL + ((size_t)(b * CIN + cc * 32 + qq * 8)) * HW_ +
                           gy * W_ + gx;
#pragma unroll
        for (int j = 0; j < 8; ++j) v[j] = (half_t)src[(size_t)j * HW_];
      }
      *(half8*)(act + pix * PITCH + qq * 8) = v;
    }
    __syncthreads();

#pragma unroll
    for (int s = 0; s < 9; ++s) {
      int ky = s / 3, kx = s - ky * 3;
      int base = (ky * 34 + kx + n) * PITCH + q * 8;
#pragma unroll
      for (int nt = 0; nt < 4; ++nt) {
        half8 bf = *(const half8*)(act + base + ntoff[nt]);
        accv[nt] =
            __builtin_amdgcn_mfma_f32_16x16x32_f16(wfrag[s], bf, accv[nt], 0, 0, 0);
      }
    }
  }

  // epilogue: fp32 store to OUT_FEAT + gn3 stats
  float sacc[4] = {0.f, 0.f, 0.f, 0.f}, qacc[4] = {0.f, 0.f, 0.f, 0.f};
#pragma unroll
  for (int nt = 0; nt < 4; ++nt) {
    int ygl = y0 + 2 * w + (nt >> 1);
    int xgl = x0 + (nt & 1) * 16 + n;
#pragma unroll
    for (int r = 0; r < 4; ++r) {
      float v = accv[nt][r];
      out[OUT_FEAT + (size_t)(b * 16 + q * 4 + r) * HW_ + ygl * W_ + xgl] = v;
      sacc[r] += v;
      qacc[r] = fmaf(v, v, qacc[r]);
    }
  }

#pragma unroll
  for (int r = 0; r < 4; ++r) {
#pragma unroll
    for (int m = 1; m < 16; m <<= 1) {
      sacc[r] += __shfl_xor(sacc[r], m);
      qacc[r] += __shfl_xor(qacc[r], m);
    }
  }
  if (n == 0) {
#pragma unroll
    for (int r = 0; r < 4; ++r) {
      redS[w][q * 4 + r] = sacc[r];
      redQ[w][q * 4 + r] = qacc[r];
    }
  }
  __syncthreads();
  if (tid < 16) {
    int g = tid >> 1;
    float v = 0.f;
    if (tid & 1) {
      for (int ww = 0; ww < 4; ++ww) v += redQ[ww][2 * g] + redQ[ww][2 * g + 1];
    } else {
      for (int ww = 0; ww < 4; ++ww) v += redS[ww][2 * g] + redS[ww][2 * g + 1];
    }
    atomicAdd(&stats[b * 16 + tid], v);
  }
}

// ============================================================
// finish: normalize+SiLU feat in place (float4), zero sx/sy.
// ============================================================
__global__ __launch_bounds__(256) void feat_finish_k(
    float* __restrict__ out, const float* __restrict__ ss) {
  int bid = blockIdx.x, tid = threadIdx.x;
  if (bid < 1024) {
    int idx4 = bid * 256 + tid;
    int bc = idx4 / 2048;
    float scv = ss[bc * 2], shv = ss[bc * 2 + 1];
    float4* p = reinterpret_cast<float4*>(out + OUT_FEAT) + idx4;
    float4 v = *p;
    float t;
    t = fmaf(v.x, scv, shv); v.x = t / (1.f + expf(-t));
    t = fmaf(v.y, scv, shv); v.y = t / (1.f + expf(-t));
    t = fmaf(v.z, scv, shv); v.z = t / (1.f + expf(-t));
    t = fmaf(v.w, scv, shv); v.w = t / (1.f + expf(-t));
    *p = v;
  } else {
    int i = (bid - 1024) * 256 + tid;
    float4 z = make_float4(0.f, 0.f, 0.f, 0.f);
    reinterpret_cast<float4*>(out + OUT_SX)[i] = z;
  }
}

// ============================================================
extern "C" void kernel_launch(void* const* d_in, const int* in_sizes, int n_in,
                              void* d_out, int out_size, void* d_ws, size_t ws_size,
                              hipStream_t stream) {
  const float* fL      = (const float*)d_in[0];
  const float* fR      = (const float*)d_in[1];
  const float* w1      = (const float*)d_in[2];
  const float* gn1_w   = (const float*)d_in[3];
  const float* gn1_b   = (const float*)d_in[4];
  const float* w2      = (const float*)d_in[5];
  const float* gn2_w   = (const float*)d_in[6];
  const float* gn2_b   = (const float*)d_in[7];
  const float* w3      = (const float*)d_in[8];
  const float* b3      = (const float*)d_in[9];
  const float* fh_w    = (const float*)d_in[10];
  const float* fh_gn_w = (const float*)d_in[11];
  const float* fh_gn_b = (const float*)d_in[12];
  float* out = (float*)d_out;
  char*  W   = (char*)d_ws;

  half_t* cvt  = (half_t*)(W + CVB);
  half_t* x1b  = (half_t*)(W + X1B);
  half_t* x2b  = (half_t*)(W + X2B);
  float*  stF  = (float*)(W + STB);
  half_t* wq1  = (half_t*)(W + WQ1B);
  half_t* wq2  = (half_t*)(W + WQ2B);
  half_t* wqf2 = (half_t*)(W + WQFB);

  hipMemsetAsync(stF, 0, ST_COUNT * sizeof(float), stream);

  prepack_k<<<114, 256, 0, stream>>>(w1, w2, fh_w, wq1, wq2, wqf2);

  cost_volume_k<<<B_ * H_ * D_, 128, 0, stream>>>(fL, fR, cvt);

  conv_mfma_k<8, false><<<768, 256, 0, stream>>>(
      cvt, wq1, x1b, stF + GN1_STATS, nullptr);
  gn_scale_k<<<1, 128, 0, stream>>>(stF + GN1_STATS, gn1_w, gn1_b,
                                    stF + GN1_SS, 1.f / 393216.f);

  conv_mfma_k<16, true><<<768, 256, 0, stream>>>(
      x1b, wq2, x2b, stF + GN2_STATS, stF + GN1_SS);
  gn_scale_k<<<1, 128, 0, stream>>>(stF + GN2_STATS, gn2_w, gn2_b,
                                    stF + GN2_SS, 1.f / 393216.f);

  conv3_softmax_k<<<B_ * 8 * 4, 256, 0, stream>>>(x2b, w3, b3,
                                                  stF + GN2_SS, out);

  feat_mfma_k<<<B_ * 8 * 4, 256, 0, stream>>>(fL, wqf2, out, stF + GN3_STATS);
  gn_scale_k<<<1, 128, 0, stream>>>(stF + GN3_STATS, fh_gn_w, fh_gn_b,
                                    stF + GN3_SS, 1.f / 16384.f);
  feat_finish_k<<<1152, 256, 0, stream>>>(out, stF + GN3_SS);
}

// Round 7
// 430.434 us; speedup vs baseline: 2.8464x; 1.0155x over previous
//
#include <hip/hip_runtime.h>
#include <math.h>

// ---------------- problem constants ----------------
#define B_   8
#define CIN  128
#define H_   64
#define W_   128
#define D_   24
#define HW_  (H_*W_)      // 8192

typedef _Float16 half_t;
typedef __attribute__((ext_vector_type(8))) _Float16 half8;
typedef __attribute__((ext_vector_type(4))) _Float16 half4;
typedef __attribute__((ext_vector_type(2))) _Float16 half2v;
typedef __attribute__((ext_vector_type(4))) float f32x4;

#if defined(__has_builtin)
#if __has_builtin(__builtin_amdgcn_fdot2)
#define FDOT2(a, b, c) __builtin_amdgcn_fdot2((a), (b), (c), false)
#endif
#endif
#ifndef FDOT2
#define FDOT2(a, b, c) ((c) + (float)(a)[0] * (float)(b)[0] + (float)(a)[1] * (float)(b)[1])
#endif

// ---------------- workspace layout (BYTE offsets) ----------------
#define CVB   0
#define X1B   25165824
#define X2B   75497472
#define STB   125829120
// float indices within stats block (float* view of STB):
#define GN1_STATS 0      // 128 floats (b,g)*2 {sum,sumsq}
#define GN1_SS    128    // 256 floats (b,c)*2 {scale,shift}
#define GN2_STATS 384
#define GN2_SS    512
#define GN3_STATS 768
#define GN3_SS    896
#define ST_COUNT  1152
#define WQ1B  (STB + 16384)          // 3584 fp16 = 7168 B   (7 ksteps)
#define WQ2B  (WQ1B + 7168)          // 7168 fp16 = 14336 B  (14 ksteps)
#define WQFB  (WQ2B + 14336)         // 18432 fp16 = 36864 B (feat, 4cc x 9s)
#define WC3B  (WQFB + 36864)         // 432 fp16 = 864 B (conv3: [tap][kz][c16])

// ---------------- output layout (float offsets in d_out) ----------------
#define OUT_D    0         // (B,1,H,W)  65536
#define OUT_SX   65536
#define OUT_SY   131072
#define OUT_FEAT 196608    // (B,16,H,W) 1048576
#define OUT_CONF 1245184

// ============================================================
// K0: prepack weights into MFMA A-fragment order (fp16).
// A[m=o][k]: lane l -> m = l&15, k = ks*32 + (l>>4)*8 + j.
// wq1: K-order tap*8+c  (7 ksteps, zero-padded past 216)
// wq2: K-order tap*16+c (14 ksteps, zero-padded past 432)
// wqf2: per 32-ch chunk cc, K-order tap-major: step s = tap, k-local = c32.
// wc3: conv3 weights fp16 [tap9][kz3][c16] for dot2 consumption.
// ============================================================
__global__ __launch_bounds__(256) void prepack_k(
    const float* __restrict__ w1, const float* __restrict__ w2,
    const float* __restrict__ fw, const float* __restrict__ w3,
    half_t* __restrict__ wq1, half_t* __restrict__ wq2,
    half_t* __restrict__ wqf2, half_t* __restrict__ wc3) {
  int i = blockIdx.x * 256 + threadIdx.x;
  if (i < 3584) {
    int s = i >> 9, l = (i >> 3) & 63, j = i & 7;
    int o = l & 15;
    int k = s * 32 + ((l >> 4) << 3) + j;
    float v = 0.f;
    if (k < 216) {
      int tap = k >> 3, c = k & 7;
      int kz = tap / 9, kyx = tap % 9;
      v = w1[((o * 8 + c) * 3 + kz) * 9 + kyx];
    }
    wq1[i] = (half_t)v;
  } else if (i < 3584 + 7168) {
    int ii = i - 3584;
    int s = ii >> 9, l = (ii >> 3) & 63, j = ii & 7;
    int o = l & 15;
    int k = s * 32 + ((l >> 4) << 3) + j;
    float v = 0.f;
    if (k < 432) {
      int tap = k >> 4, c = k & 15;
      int kz = tap / 9, kyx = tap % 9;
      v = w2[((o * 16 + c) * 3 + kz) * 9 + kyx];
    }
    wq2[ii] = (half_t)v;
  } else if (i < 3584 + 7168 + 18432) {
    int jj = i - (3584 + 7168);
    int cc = jj / 4608, rem = jj % 4608;
    int s = rem >> 9, l = (rem >> 3) & 63, j = rem & 7;
    int o = l & 15;
    int c = cc * 32 + ((l >> 4) << 3) + j;
    wqf2[jj] = (half_t)fw[(o * CIN + c) * 9 + s];   // s = ky*3+kx
  } else if (i < 3584 + 7168 + 18432 + 432) {
    int jj = i - (3584 + 7168 + 18432);
    int c = jj & 15, tk = jj >> 4;
    int kz = tk % 3, tap = tk / 3;
    wc3[jj] = (half_t)w3[c * 27 + kz * 9 + tap];    // w3 layout [c][kz][kyx]
  }
}

// ============================================================
// K1: cost volume -> fp16 [b][d][y][x][g8]
// ============================================================
__global__ __launch_bounds__(128) void cost_volume_k(
    const float* __restrict__ fL, const float* __restrict__ fR,
    half_t* __restrict__ cvt) {
  int w  = threadIdx.x;
  int d  = blockIdx.x % D_;
  int bh = blockIdx.x / D_;
  int h  = bh & 63;
  int b  = bh >> 6;

  float acc[8];
#pragma unroll
  for (int g = 0; g < 8; ++g) acc[g] = 0.f;

  int wr = w - d;
  if (wr >= 0) {
    const float* pL = fL + (size_t)b * CIN * HW_ + h * W_ + w;
    const float* pR = fR + (size_t)b * CIN * HW_ + h * W_ + wr;
#pragma unroll
    for (int g = 0; g < 8; ++g) {
      float a = 0.f;
#pragma unroll
      for (int ci = 0; ci < 16; ++ci) {
        int c = g * 16 + ci;
        a = fmaf(pL[(size_t)c * HW_], pR[(size_t)c * HW_], a);
      }
      acc[g] = a;
    }
  }
  size_t p = (((size_t)b * D_ + d) * H_ + h) * W_ + w;
  half8 ov;
#pragma unroll
  for (int g = 0; g < 8; ++g) ov[g] = (half_t)(acc[g] * 0.0625f);
  *(half8*)(cvt + p * 8) = ov;
}

// ============================================================
// MFMA conv3d 3x3x3 CI->16 (unchanged from round 3, verified).
// ============================================================
template <int CI, bool NORM>
__global__ __launch_bounds__(256, 2) void conv_mfma_k(
    const half_t* __restrict__ in, const half_t* __restrict__ wq,
    half_t* __restrict__ outp, float* __restrict__ stats,
    const float* __restrict__ nss) {
  constexpr int KS    = (CI == 16) ? 14 : 7;
  constexpr int PITCH = (CI == 16) ? 24 : 8;
  constexpr int TPS   = 32 / CI;

  __shared__ half_t act[3 * 340 * PITCH];
  __shared__ float redS[4][16], redQ[4][16];

  int tid = threadIdx.x;
  int l = tid & 63, w = tid >> 6;
  int bid = blockIdx.x;
  int xt = bid & 3, yt = (bid >> 2) & 7;
  int r5 = bid >> 5;
  int zc = r5 % 3, b = r5 / 3;
  int z0 = zc * 8;
  int y0 = yt * 8, x0 = xt * 32;

  half8 wfrag[KS];
#pragma unroll
  for (int s = 0; s < KS; ++s)
    wfrag[s] = *(const half8*)(wq + (s * 64 + l) * 8);

  float sc[8], sh[8];
  if (NORM) {
    int c0 = (tid & 1) * 8;
#pragma unroll
    for (int j = 0; j < 8; ++j) {
      sc[j] = nss[b * 32 + (c0 + j) * 2];
      sh[j] = nss[b * 32 + (c0 + j) * 2 + 1];
    }
  }

  auto fill = [&](int zi, int slot) {
    if (CI == 16) {
      for (int u = tid; u < 680; u += 256) {
        int chunk = u & 1, pix = u >> 1;
        int yy = pix / 34, xx = pix - yy * 34;
        int gy = y0 - 1 + yy, gx = x0 - 1 + xx;
        half8 v = {0, 0, 0, 0, 0, 0, 0, 0};
        if ((unsigned)zi < 24u && (unsigned)gy < 64u && (unsigned)gx < 128u) {
          half8 rr = *(const half8*)(in +
              ((((size_t)b * D_ + zi) * H_ + gy) * W_ + gx) * 16 + chunk * 8);
          if (NORM) {
#pragma unroll
            for (int j = 0; j < 8; ++j) {
              float t = fmaf((float)rr[j], sc[j], sh[j]);
              v[j] = (half_t)(t / (1.f + __expf(-t)));
            }
          } else {
            v = rr;
          }
        }
        *(half8*)(act + (slot * 340 + pix) * PITCH + chunk * 8) = v;
      }
    } else {
      for (int u = tid; u < 340; u += 256) {
        int yy = u / 34, xx = u - yy * 34;
        int gy = y0 - 1 + yy, gx = x0 - 1 + xx;
        half8 v = {0, 0, 0, 0, 0, 0, 0, 0};
        if ((unsigned)zi < 24u && (unsigned)gy < 64u && (unsigned)gx < 128u)
          v = *(const half8*)(in +
              ((((size_t)b * D_ + zi) * H_ + gy) * W_ + gx) * 8);
        *(half8*)(act + (slot * 340 + u) * PITCH) = v;
      }
    }
  };

  int q = l >> 4, n = l & 15;
  int chalf  = (CI == 16) ? (q & 1) * 8 : 0;
  int tapadd = (CI == 16) ? (q >> 1) : q;
  int ntoff[4];
#pragma unroll
  for (int nt = 0; nt < 4; ++nt)
    ntoff[nt] = ((2 * w + (nt >> 1)) * 34 + (nt & 1) * 16) * PITCH;

  float sacc[4] = {0.f, 0.f, 0.f, 0.f}, qacc[4] = {0.f, 0.f, 0.f, 0.f};

  fill(z0 - 1, z0 % 3);
  fill(z0, (z0 + 1) % 3);

  for (int z = z0; z < z0 + 8; ++z) {
    fill(z + 1, (z + 2) % 3);
    __syncthreads();
    int zm3 = z % 3;

    f32x4 accv[4];
#pragma unroll
    for (int nt = 0; nt < 4; ++nt) accv[nt] = (f32x4){0.f, 0.f, 0.f, 0.f};

#pragma unroll
    for (int s = 0; s < KS; ++s) {
      int tap = TPS * s + tapadd;
      tap = tap > 26 ? 26 : tap;
      int kz = (tap * 57) >> 9;
      int t9 = tap - kz * 9;
      int ky = (t9 * 11) >> 5;
      int kx = t9 - ky * 3;
      int sl = zm3 + kz; if (sl >= 3) sl -= 3;
      int base = (sl * 340 + ky * 34 + kx + n) * PITCH + chalf;
#pragma unroll
      for (int nt = 0; nt < 4; ++nt) {
        half8 bf = *(const half8*)(act + base + ntoff[nt]);
        accv[nt] =
            __builtin_amdgcn_mfma_f32_16x16x32_f16(wfrag[s], bf, accv[nt], 0, 0, 0);
      }
    }

#pragma unroll
    for (int nt = 0; nt < 4; ++nt) {
      int ygl = y0 + 2 * w + (nt >> 1);
      int xgl = x0 + (nt & 1) * 16 + n;
      half4 o;
#pragma unroll
      for (int r = 0; r < 4; ++r) {
        float v = accv[nt][r];
        o[r] = (half_t)v;
        sacc[r] += v;
        qacc[r] = fmaf(v, v, qacc[r]);
      }
      *(half4*)(outp + ((((size_t)b * D_ + z) * H_ + ygl) * W_ + xgl) * 16 +
                q * 4) = o;
    }
    __syncthreads();
  }

#pragma unroll
  for (int r = 0; r < 4; ++r) {
#pragma unroll
    for (int m = 1; m < 16; m <<= 1) {
      sacc[r] += __shfl_xor(sacc[r], m);
      qacc[r] += __shfl_xor(qacc[r], m);
    }
  }
  if (n == 0) {
#pragma unroll
    for (int r = 0; r < 4; ++r) {
      redS[w][q * 4 + r] = sacc[r];
      redQ[w][q * 4 + r] = qacc[r];
    }
  }
  __syncthreads();
  if (tid < 16) {
    int g = tid >> 1;
    float v = 0.f;
    if (tid & 1) {
      for (int ww = 0; ww < 4; ++ww) v += redQ[ww][2 * g] + redQ[ww][2 * g + 1];
    } else {
      for (int ww = 0; ww < 4; ++ww) v += redS[ww][2 * g] + redS[ww][2 * g + 1];
    }
    atomicAdd(&stats[b * 16 + tid], v);
  }
}

// ============================================================
// stats -> per (b,c) scale/shift
// ============================================================
__global__ __launch_bounds__(128) void gn_scale_k(
    const float* __restrict__ stats, const float* __restrict__ gw,
    const float* __restrict__ gb, float* __restrict__ ss, float inv_count) {
  int i = threadIdx.x;
  if (i < 128) {
    int c = i & 15, g = c >> 1, b = i >> 4;
    float sum = stats[(b * 8 + g) * 2];
    float sq  = stats[(b * 8 + g) * 2 + 1];
    float mean = sum * inv_count;
    float var  = sq * inv_count - mean * mean;
    float rstd = rsqrtf(var + 1e-5f);
    float scv = gw[c] * rstd;
    ss[i * 2] = scv;
    ss[i * 2 + 1] = gb[c] - mean * scv;
  }
}

// ============================================================
// conv3d 16->1 fused with softmax over D (v2).
// 512 threads: waves 0-3 own channels 0-7, waves 4-7 own channels 8-15
// (weights wave-uniform -> SGPR path); pixel = tid&255 of an 8x32 tile.
// Plane: fp16 [2][340 pix][pitch 40] ping-pong (single sync per zp);
// pitch 40 halfs = 20-word lane stride -> conflict-free ds_read_b128.
// Logits accumulate in 26 REGISTERS (zp fully unrolled). Softmax bias
// dropped (uniform bias cancels in softmax). Partial cross-wave combine
// via LDS aliased over the plane pool (sync-guarded).
// ============================================================
__global__ __launch_bounds__(512) void conv3_softmax_k(
    const half_t* __restrict__ x2, const half_t* __restrict__ wc3,
    const float* __restrict__ nss, float* __restrict__ out) {
  constexpr int PITCH = 40;
  __shared__ char pool[2 * 340 * PITCH * 2];   // 54400 B
  half_t* plane = (half_t*)pool;               // [2][340*PITCH]
  float* part = (float*)pool;                  // [256][25], used after sync

  int tid = threadIdx.x;
  int xt = blockIdx.x & 3;
  int yt = (blockIdx.x >> 2) & 7;
  int b  = blockIdx.x >> 5;
  int y0 = yt * 8, x0 = xt * 32;

  // fill-role gn2 scale/shift (by tid parity; fill chunk = u&1 = tid&1)
  float sc[8], sh[8];
  {
    int c0 = (tid & 1) * 8;
#pragma unroll
    for (int j = 0; j < 8; ++j) {
      sc[j] = nss[b * 32 + (c0 + j) * 2];
      sh[j] = nss[b * 32 + (c0 + j) * 2 + 1];
    }
  }

  // compute-role: wave-chunk of channels
  int wv = tid >> 6;
  int ch = (wv >= 4) ? 8 : 0;          // wave-uniform
  int pix = tid & 255;
  int py = pix >> 5, px = pix & 31;
  const uint* wu = (const uint*)wc3;   // [tap][kz][8 pairs]

  auto fill = [&](int zf, int buf) {
    for (int u = tid; u < 680; u += 512) {
      int chunk = u & 1, p = u >> 1;
      int yy = p / 34, xx = p - yy * 34;
      int gy = y0 - 1 + yy, gx = x0 - 1 + xx;
      half8 v = {0, 0, 0, 0, 0, 0, 0, 0};
      if ((unsigned)gy < 64u && (unsigned)gx < 128u) {
        half8 rr = *(const half8*)(x2 +
            ((((size_t)b * D_ + zf) * H_ + gy) * W_ + gx) * 16 + chunk * 8);
#pragma unroll
        for (int j = 0; j < 8; ++j) {
          float t = fmaf((float)rr[j], sc[j], sh[j]);
          v[j] = (half_t)(t / (1.f + __expf(-t)));
        }
      }
      *(half8*)(plane + (buf * 340 + p) * PITCH + chunk * 8) = v;
    }
  };

  float l[26];
#pragma unroll
  for (int z = 0; z < 26; ++z) l[z] = 0.f;

  fill(0, 0);

#pragma unroll
  for (int zp = 0; zp < D_; ++zp) {
    __syncthreads();                    // fill(zp) complete
    if (zp < D_ - 1) fill(zp + 1, (zp + 1) & 1);
    const half_t* pb = plane + ((zp & 1) * 340) * PITCH + ch;
#pragma unroll
    for (int tap = 0; tap < 9; ++tap) {
      int ky = tap / 3, kx = tap - ky * 3;
      half8 av = *(const half8*)(pb + ((py + ky) * 34 + px + kx) * PITCH);
      half2v pa0 = {av[0], av[1]}, pa1 = {av[2], av[3]};
      half2v pa2 = {av[4], av[5]}, pa3 = {av[6], av[7]};
#pragma unroll
      for (int kz = 0; kz < 3; ++kz) {
        const uint* wb = wu + (tap * 3 + kz) * 8 + (ch >> 1);
        union { uint u; half2v h; } w0, w1, w2t, w3t;
        w0.u = wb[0]; w1.u = wb[1]; w2t.u = wb[2]; w3t.u = wb[3];
        float a = l[zp + 2 - kz];
        a = FDOT2(pa0, w0.h, a);
        a = FDOT2(pa1, w1.h, a);
        a = FDOT2(pa2, w2t.h, a);
        a = FDOT2(pa3, w3t.h, a);
        l[zp + 2 - kz] = a;
      }
    }
  }

  __syncthreads();                      // all plane reads done (alias guard)
  if (wv >= 4) {
#pragma unroll
    for (int z = 0; z < 24; ++z) part[pix * 25 + z] = l[z + 1];
  }
  __syncthreads();
  if (wv < 4) {
    float lv[24], m = -1e30f;
#pragma unroll
    for (int z = 0; z < 24; ++z) {
      lv[z] = l[z + 1] + part[pix * 25 + z];
      m = fmaxf(m, lv[z]);
    }
    float s = 0.f, ds = 0.f;
#pragma unroll
    for (int z = 0; z < 24; ++z) {
      float e = __expf(lv[z] - m);
      s += e;
      ds = fmaf(e, (float)z, ds);
    }
    float inv = 1.f / s;
    int y = y0 + py, x = x0 + px;
    out[OUT_D    + b * HW_ + y * W_ + x] = ds * inv;
    out[OUT_CONF + b * HW_ + y * W_ + x] = inv;   // max prob = exp(0)/s
  }
}

// ============================================================
// feat head: MFMA conv2d 128->16 3x3 SAME on fL (verified round 6).
// ============================================================
__global__ __launch_bounds__(256, 2) void feat_mfma_k(
    const float* __restrict__ fL, const half_t* __restrict__ wqf2,
    float* __restrict__ out, float* __restrict__ stats) {
  constexpr int PITCH = 40;

  __shared__ half_t act[340 * PITCH];   // 27200 B
  __shared__ float redS[4][16], redQ[4][16];

  int tid = threadIdx.x;
  int l = tid & 63, w = tid >> 6;
  int xt = blockIdx.x & 3;
  int yt = (blockIdx.x >> 2) & 7;
  int b  = blockIdx.x >> 5;
  int y0 = yt * 8, x0 = xt * 32;

  int q = l >> 4, n = l & 15;
  int ntoff[4];
#pragma unroll
  for (int nt = 0; nt < 4; ++nt)
    ntoff[nt] = ((2 * w + (nt >> 1)) * 34 + (nt & 1) * 16) * PITCH;

  f32x4 accv[4];
#pragma unroll
  for (int nt = 0; nt < 4; ++nt) accv[nt] = (f32x4){0.f, 0.f, 0.f, 0.f};

  for (int cc = 0; cc < 4; ++cc) {
    half8 wfrag[9];
#pragma unroll
    for (int s = 0; s < 9; ++s)
      wfrag[s] = *(const half8*)(wqf2 + ((cc * 9 + s) * 64 + l) * 8);

    __syncthreads();
    for (int u = tid; u < 1360; u += 256) {
      int qq = u & 3, pix = u >> 2;
      int yy = pix / 34, xx = pix - yy * 34;
      int gy = y0 - 1 + yy, gx = x0 - 1 + xx;
      half8 v = {0, 0, 0, 0, 0, 0, 0, 0};
      if ((unsigned)gy < 64u && (unsigned)gx < 128u) {
        const float* src = fL + ((size_t)(b * CIN + cc * 32 + qq * 8)) * HW_ +
                           gy * W_ + gx;
#pragma unroll
        for (int j = 0; j < 8; ++j) v[j] = (half_t)src[(size_t)j * HW_];
      }
      *(half8*)(act + pix * PITCH + qq * 8) = v;
    }
    __syncthreads();

#pragma unroll
    for (int s = 0; s < 9; ++s) {
      int ky = s / 3, kx = s - ky * 3;
      int base = (ky * 34 + kx + n) * PITCH + q * 8;
#pragma unroll
      for (int nt = 0; nt < 4; ++nt) {
        half8 bf = *(const half8*)(act + base + ntoff[nt]);
        accv[nt] =
            __builtin_amdgcn_mfma_f32_16x16x32_f16(wfrag[s], bf, accv[nt], 0, 0, 0);
      }
    }
  }

  float sacc[4] = {0.f, 0.f, 0.f, 0.f}, qacc[4] = {0.f, 0.f, 0.f, 0.f};
#pragma unroll
  for (int nt = 0; nt < 4; ++nt) {
    int ygl = y0 + 2 * w + (nt >> 1);
    int xgl = x0 + (nt & 1) * 16 + n;
#pragma unroll
    for (int r = 0; r < 4; ++r) {
      float v = accv[nt][r];
      out[OUT_FEAT + (size_t)(b * 16 + q * 4 + r) * HW_ + ygl * W_ + xgl] = v;
      sacc[r] += v;
      qacc[r] = fmaf(v, v, qacc[r]);
    }
  }

#pragma unroll
  for (int r = 0; r < 4; ++r) {
#pragma unroll
    for (int m = 1; m < 16; m <<= 1) {
      sacc[r] += __shfl_xor(sacc[r], m);
      qacc[r] += __shfl_xor(qacc[r], m);
    }
  }
  if (n == 0) {
#pragma unroll
    for (int r = 0; r < 4; ++r) {
      redS[w][q * 4 + r] = sacc[r];
      redQ[w][q * 4 + r] = qacc[r];
    }
  }
  __syncthreads();
  if (tid < 16) {
    int g = tid >> 1;
    float v = 0.f;
    if (tid & 1) {
      for (int ww = 0; ww < 4; ++ww) v += redQ[ww][2 * g] + redQ[ww][2 * g + 1];
    } else {
      for (int ww = 0; ww < 4; ++ww) v += redS[ww][2 * g] + redS[ww][2 * g + 1];
    }
    atomicAdd(&stats[b * 16 + tid], v);
  }
}

// ============================================================
// finish: normalize+SiLU feat in place (float4), zero sx/sy.
// ============================================================
__global__ __launch_bounds__(256) void feat_finish_k(
    float* __restrict__ out, const float* __restrict__ ss) {
  int bid = blockIdx.x, tid = threadIdx.x;
  if (bid < 1024) {
    int idx4 = bid * 256 + tid;
    int bc = idx4 / 2048;
    float scv = ss[bc * 2], shv = ss[bc * 2 + 1];
    float4* p = reinterpret_cast<float4*>(out + OUT_FEAT) + idx4;
    float4 v = *p;
    float t;
    t = fmaf(v.x, scv, shv); v.x = t / (1.f + expf(-t));
    t = fmaf(v.y, scv, shv); v.y = t / (1.f + expf(-t));
    t = fmaf(v.z, scv, shv); v.z = t / (1.f + expf(-t));
    t = fmaf(v.w, scv, shv); v.w = t / (1.f + expf(-t));
    *p = v;
  } else {
    int i = (bid - 1024) * 256 + tid;
    float4 z = make_float4(0.f, 0.f, 0.f, 0.f);
    reinterpret_cast<float4*>(out + OUT_SX)[i] = z;
  }
}

// ============================================================
extern "C" void kernel_launch(void* const* d_in, const int* in_sizes, int n_in,
                              void* d_out, int out_size, void* d_ws, size_t ws_size,
                              hipStream_t stream) {
  const float* fL      = (const float*)d_in[0];
  const float* fR      = (const float*)d_in[1];
  const float* w1      = (const float*)d_in[2];
  const float* gn1_w   = (const float*)d_in[3];
  const float* gn1_b   = (const float*)d_in[4];
  const float* w2      = (const float*)d_in[5];
  const float* gn2_w   = (const float*)d_in[6];
  const float* gn2_b   = (const float*)d_in[7];
  const float* w3      = (const float*)d_in[8];
  const float* fh_w    = (const float*)d_in[10];
  const float* fh_gn_w = (const float*)d_in[11];
  const float* fh_gn_b = (const float*)d_in[12];
  float* out = (float*)d_out;
  char*  W   = (char*)d_ws;

  half_t* cvt  = (half_t*)(W + CVB);
  half_t* x1b  = (half_t*)(W + X1B);
  half_t* x2b  = (half_t*)(W + X2B);
  float*  stF  = (float*)(W + STB);
  half_t* wq1  = (half_t*)(W + WQ1B);
  half_t* wq2  = (half_t*)(W + WQ2B);
  half_t* wqf2 = (half_t*)(W + WQFB);
  half_t* wc3  = (half_t*)(W + WC3B);

  hipMemsetAsync(stF, 0, ST_COUNT * sizeof(float), stream);

  prepack_k<<<116, 256, 0, stream>>>(w1, w2, fh_w, w3, wq1, wq2, wqf2, wc3);

  cost_volume_k<<<B_ * H_ * D_, 128, 0, stream>>>(fL, fR, cvt);

  conv_mfma_k<8, false><<<768, 256, 0, stream>>>(
      cvt, wq1, x1b, stF + GN1_STATS, nullptr);
  gn_scale_k<<<1, 128, 0, stream>>>(stF + GN1_STATS, gn1_w, gn1_b,
                                    stF + GN1_SS, 1.f / 393216.f);

  conv_mfma_k<16, true><<<768, 256, 0, stream>>>(
      x1b, wq2, x2b, stF + GN2_STATS, stF + GN1_SS);
  gn_scale_k<<<1, 128, 0, stream>>>(stF + GN2_STATS, gn2_w, gn2_b,
                                    stF + GN2_SS, 1.f / 393216.f);

  conv3_softmax_k<<<B_ * 8 * 4, 512, 0, stream>>>(x2b, wc3, stF + GN2_SS, out);

  feat_mfma_k<<<B_ * 8 * 4, 256, 0, stream>>>(fL, wqf2, out, stF + GN3_STATS);
  gn_scale_k<<<1, 128, 0, stream>>>(stF + GN3_STATS, fh_gn_w, fh_gn_b,
                                    stF + GN3_SS, 1.f / 16384.f);
  feat_finish_k<<<1152, 256, 0, stream>>>(out, stF + GN3_SS);
}